// Round 1
// baseline (1026.445 us; speedup 1.0000x reference)
//
#include <hip/hip_runtime.h>
#include <cstdint>
#include <cstddef>

#define B_DIM 16
#define C_DIM 512
#define D_DIM 512
#define N_DIM 2048

typedef _Float16 half8  __attribute__((ext_vector_type(8)));
typedef _Float16 half4v __attribute__((ext_vector_type(4)));
typedef float    floatx4 __attribute__((ext_vector_type(4)));

// ---------------------------------------------------------------------------
// NT GEMM: C[M,Ncols] (f32) = A[M,K] (f16 row-major) * B[Ncols,K]^T (f16 rm)
// 128x128 tile, BK=32, 4 waves (2x2), 4x4 16x16x32 MFMA frags per wave.
// EPI==1: C = beta*acc + (float)H   (H laid out like C)
// ---------------------------------------------------------------------------
template<int EPI>
__global__ __launch_bounds__(256, 2)
void gemm_nt(const _Float16* __restrict__ A, size_t strideA,
             const _Float16* __restrict__ Bm, size_t strideB,
             float* __restrict__ Cm, size_t strideC,
             int M, int Ncols, int K,
             const float* __restrict__ beta_ptr,
             const _Float16* __restrict__ Hm, size_t strideH)
{
    constexpr int BK  = 32;
    constexpr int LDK = 40;                 // padded row stride (halfs): 80B -> 2-way LDS aliasing (free)
    __shared__ _Float16 sA[128 * LDK];
    __shared__ _Float16 sB[128 * LDK];

    const int bz = blockIdx.z;
    const _Float16* Ab = A  + (size_t)bz * strideA;
    const _Float16* Bb = Bm + (size_t)bz * strideB;

    const int m0 = blockIdx.x * 128;
    const int n0 = blockIdx.y * 128;

    const int tid  = threadIdx.x;
    const int lane = tid & 63;
    const int wr   = (tid >> 7) & 1;        // wave row (2x2 waves, 64x64 out each)
    const int wc   = (tid >> 6) & 1;        // wave col

    // staging: flat f = pass*256 + tid ; row = f>>2 ; 8-half chunk = f&3
    const int r0 = tid >> 2;
    const int c0 = (tid & 3) * 8;

    const _Float16* gA0 = Ab + (size_t)(m0 + r0)      * K + c0;
    const _Float16* gA1 = Ab + (size_t)(m0 + r0 + 64) * K + c0;
    const _Float16* gB0 = Bb + (size_t)(n0 + r0)      * K + c0;
    const _Float16* gB1 = Bb + (size_t)(n0 + r0 + 64) * K + c0;

    _Float16* sA0 = &sA[(r0     ) * LDK + c0];
    _Float16* sA1 = &sA[(r0 + 64) * LDK + c0];
    _Float16* sB0 = &sB[(r0     ) * LDK + c0];
    _Float16* sB1 = &sB[(r0 + 64) * LDK + c0];

    // fragment read addresses: A row = lane&15, k = (lane>>4)*8 + e (contiguous 8)
    const int fr = lane & 15;
    const int fk = (lane >> 4) * 8;
    const _Float16* fA = &sA[(wr * 64 + fr) * LDK + fk];
    const _Float16* fB = &sB[(wc * 64 + fr) * LDK + fk];

    floatx4 acc[4][4] = {};

    // prologue loads (tile 0)
    half8 ra0 = *(const half8*)gA0;
    half8 ra1 = *(const half8*)gA1;
    half8 rb0 = *(const half8*)gB0;
    half8 rb1 = *(const half8*)gB1;

    for (int k0 = 0; k0 < K; k0 += BK) {
        __syncthreads();                    // previous compute done reading LDS
        *(half8*)sA0 = ra0;
        *(half8*)sA1 = ra1;
        *(half8*)sB0 = rb0;
        *(half8*)sB1 = rb1;
        __syncthreads();                    // tile visible
        if (k0 + BK < K) {                  // prefetch next tile; latency hides under MFMA phase
            gA0 += BK; gA1 += BK; gB0 += BK; gB1 += BK;
            ra0 = *(const half8*)gA0;
            ra1 = *(const half8*)gA1;
            rb0 = *(const half8*)gB0;
            rb1 = *(const half8*)gB1;
        }
        half8 af[4], bf[4];
        #pragma unroll
        for (int i = 0; i < 4; ++i) af[i] = *(const half8*)(fA + i * 16 * LDK);
        #pragma unroll
        for (int j = 0; j < 4; ++j) bf[j] = *(const half8*)(fB + j * 16 * LDK);
        #pragma unroll
        for (int i = 0; i < 4; ++i)
            #pragma unroll
            for (int j = 0; j < 4; ++j)
                acc[i][j] = __builtin_amdgcn_mfma_f32_16x16x32_f16(af[i], bf[j], acc[i][j], 0, 0, 0);
    }

    float beta = 0.0f;
    const _Float16* Hb = nullptr;
    if (EPI == 1) { beta = beta_ptr[0]; Hb = Hm + (size_t)bz * strideH; }
    float* Cb = Cm + (size_t)bz * strideC;

    // C/D layout (verified): col = lane&15, row = (lane>>4)*4 + r
    #pragma unroll
    for (int i = 0; i < 4; ++i) {
        const int rowb = m0 + wr * 64 + i * 16 + ((lane >> 4) << 2);
        #pragma unroll
        for (int j = 0; j < 4; ++j) {
            const int col = n0 + wc * 64 + j * 16 + (lane & 15);
            #pragma unroll
            for (int r = 0; r < 4; ++r) {
                size_t idx = (size_t)(rowb + r) * Ncols + col;
                float v = acc[i][j][r];
                if (EPI == 1) v = beta * v + (float)Hb[idx];
                Cb[idx] = v;
            }
        }
    }
}

// ---------------------------------------------------------------------------
__global__ void convert_w_kernel(const float* __restrict__ W, _Float16* __restrict__ Wh, int n)
{
    int i = blockIdx.x * 256 + threadIdx.x;
    if (i < n) Wh[i] = (_Float16)W[i];
}

// x [B,C,N] f32 -> xT [B,N,C] f16   (32x32 LDS tile transpose)
__global__ void transpose_convert_x(const float* __restrict__ x, _Float16* __restrict__ xT)
{
    __shared__ float tile[32][33];
    const int bz = blockIdx.z;
    const int n0 = blockIdx.x * 32;
    const int c0 = blockIdx.y * 32;
    const int tx = threadIdx.x, ty = threadIdx.y;
    const float* xb = x + (size_t)bz * C_DIM * N_DIM;
    #pragma unroll
    for (int j = 0; j < 4; ++j)
        tile[ty + j * 8][tx] = xb[(size_t)(c0 + ty + j * 8) * N_DIM + n0 + tx];
    __syncthreads();
    _Float16* xtb = xT + (size_t)bz * N_DIM * C_DIM;
    #pragma unroll
    for (int j = 0; j < 4; ++j)
        xtb[(size_t)(n0 + ty + j * 8) * C_DIM + c0 + tx] = (_Float16)tile[tx][ty + j * 8];
}

// per-channel BN stats over (B,N): stats[d] = (scale, bias)
__global__ __launch_bounds__(256)
void bn_stats(const float* __restrict__ q, const float* __restrict__ gamma,
              const float* __restrict__ bn_beta, float2* __restrict__ stats)
{
    const int d = blockIdx.x;
    const int tid = threadIdx.x;
    float s = 0.f, ss = 0.f;
    for (int b = 0; b < B_DIM; ++b) {
        const float* row = q + ((size_t)b * D_DIM + d) * N_DIM;
        for (int i = tid * 4; i < N_DIM; i += 1024) {
            float4 v = *(const float4*)(row + i);
            s  += v.x + v.y + v.z + v.w;
            ss += v.x * v.x + v.y * v.y + v.z * v.z + v.w * v.w;
        }
    }
    #pragma unroll
    for (int off = 32; off; off >>= 1) {
        s  += __shfl_down(s,  off, 64);
        ss += __shfl_down(ss, off, 64);
    }
    __shared__ float red[8];
    const int wv = tid >> 6;
    if ((tid & 63) == 0) { red[wv] = s; red[4 + wv] = ss; }
    __syncthreads();
    if (tid == 0) {
        s  = red[0] + red[1] + red[2] + red[3];
        ss = red[4] + red[5] + red[6] + red[7];
        const float inv = 1.0f / (float)(B_DIM * N_DIM);
        float mean = s * inv;
        float var  = ss * inv - mean * mean;
        float scale = gamma[d] * rsqrtf(var + 1e-5f);
        stats[d] = make_float2(scale, bn_beta[d] - mean * scale);
    }
}

__device__ inline float mishf(float v)
{
    float sp = (v > 0.f) ? (v + log1pf(expf(-v))) : log1pf(expf(v));
    return v * tanhf(sp);
}

// q [B,D,N] f32 -> h [B,D,N] f16  and  hT [B,N,D] f16 (BN + mish fused, tiled transpose)
__global__ void bn_mish(const float* __restrict__ q, const float2* __restrict__ stats,
                        _Float16* __restrict__ h, _Float16* __restrict__ hT)
{
    __shared__ float tile[32][33];
    const int bz = blockIdx.z;
    const int n0 = blockIdx.x * 32;
    const int d0 = blockIdx.y * 32;
    const int tx = threadIdx.x, ty = threadIdx.y;
    const float* qb = q + (size_t)bz * D_DIM * N_DIM;
    _Float16* hb = h + (size_t)bz * D_DIM * N_DIM;
    #pragma unroll
    for (int j = 0; j < 4; ++j) {
        int d = d0 + ty + j * 8;
        float2 sc = stats[d];
        float v  = qb[(size_t)d * N_DIM + n0 + tx];
        float hv = mishf(v * sc.x + sc.y);
        tile[ty + j * 8][tx] = hv;
        hb[(size_t)d * N_DIM + n0 + tx] = (_Float16)hv;
    }
    __syncthreads();
    _Float16* htb = hT + (size_t)bz * N_DIM * D_DIM;
    #pragma unroll
    for (int j = 0; j < 4; ++j)
        htb[(size_t)(n0 + ty + j * 8) * D_DIM + d0 + tx] = (_Float16)tile[tx][ty + j * 8];
}

// row softmax: energy [*,N] f32 -> attn [*,N] f16, one block per row
__global__ __launch_bounds__(256)
void softmax_rows(const float* __restrict__ energy, size_t strideE,
                  _Float16* __restrict__ attn, size_t strideAt)
{
    const int n = blockIdx.x;
    const int b = blockIdx.y;
    const float* row = energy + (size_t)b * strideE + (size_t)n * N_DIM;
    _Float16*   orow = attn   + (size_t)b * strideAt + (size_t)n * N_DIM;
    const int tid = threadIdx.x;
    float4 v0 = *(const float4*)(row + tid * 4);
    float4 v1 = *(const float4*)(row + 1024 + tid * 4);
    float mx = fmaxf(fmaxf(fmaxf(v0.x, v0.y), fmaxf(v0.z, v0.w)),
                     fmaxf(fmaxf(v1.x, v1.y), fmaxf(v1.z, v1.w)));
    #pragma unroll
    for (int off = 32; off; off >>= 1) mx = fmaxf(mx, __shfl_down(mx, off, 64));
    __shared__ float redm[4], reds[4];
    const int wv = tid >> 6;
    if ((tid & 63) == 0) redm[wv] = mx;
    __syncthreads();
    mx = fmaxf(fmaxf(redm[0], redm[1]), fmaxf(redm[2], redm[3]));
    float e0 = __expf(v0.x - mx), e1 = __expf(v0.y - mx), e2 = __expf(v0.z - mx), e3 = __expf(v0.w - mx);
    float e4 = __expf(v1.x - mx), e5 = __expf(v1.y - mx), e6 = __expf(v1.z - mx), e7 = __expf(v1.w - mx);
    float s = e0 + e1 + e2 + e3 + e4 + e5 + e6 + e7;
    #pragma unroll
    for (int off = 32; off; off >>= 1) s += __shfl_down(s, off, 64);
    if ((tid & 63) == 0) reds[wv] = s;
    __syncthreads();
    s = reds[0] + reds[1] + reds[2] + reds[3];
    const float inv = 1.0f / s;
    half4v o0 = { (_Float16)(e0 * inv), (_Float16)(e1 * inv), (_Float16)(e2 * inv), (_Float16)(e3 * inv) };
    half4v o1 = { (_Float16)(e4 * inv), (_Float16)(e5 * inv), (_Float16)(e6 * inv), (_Float16)(e7 * inv) };
    *(half4v*)(orow + tid * 4)        = o0;
    *(half4v*)(orow + 1024 + tid * 4) = o1;
}

// ---------------------------------------------------------------------------
extern "C" void kernel_launch(void* const* d_in, const int* in_sizes, int n_in,
                              void* d_out, int out_size, void* d_ws, size_t ws_size,
                              hipStream_t stream)
{
    const float* x       = (const float*)d_in[0];
    const float* W       = (const float*)d_in[1];
    const float* gamma   = (const float*)d_in[2];
    const float* bn_beta = (const float*)d_in[3];
    const float* beta    = (const float*)d_in[4];
    float* out = (float*)d_out;

    char* ws = (char*)d_ws;
    size_t off = 0;
    auto take = [&](size_t bytes) -> char* {
        char* p = ws + off;
        off = (off + bytes + 255) & ~(size_t)255;
        return p;
    };

    _Float16* xT    = (_Float16*)take((size_t)B_DIM * N_DIM * C_DIM * 2);  // later aliased as hT
    float*    q     = (float*)   take((size_t)B_DIM * D_DIM * N_DIM * 4);
    _Float16* h     = (_Float16*)take((size_t)B_DIM * D_DIM * N_DIM * 2);
    _Float16* Wh    = (_Float16*)take((size_t)D_DIM * C_DIM * 2);
    float2*   stats = (float2*)  take((size_t)D_DIM * sizeof(float2));
    _Float16* hT    = xT;                                                   // xT dead after GEMM1

    const size_t eSz = (size_t)N_DIM * N_DIM * 4;   // fp32 energy per batch
    const size_t aSz = (size_t)N_DIM * N_DIM * 2;   // fp16 attn per batch
    const size_t fixedEnd = off;

    int eb, ab;  // batches materialized for energy / attn
    if      (ws_size >= fixedEnd + 16 * eSz + 16 * aSz + 1024) { eb = 16; ab = 16; }
    else if (ws_size >= fixedEnd +      eSz + 16 * aSz + 1024) { eb = 1;  ab = 16; }
    else                                                        { eb = 1;  ab = 1;  }

    float*    energy = (float*)   take((size_t)eb * eSz);
    _Float16* attn   = (_Float16*)take((size_t)ab * aSz);

    // 1. W -> f16
    convert_w_kernel<<<dim3((D_DIM * C_DIM + 255) / 256), dim3(256), 0, stream>>>(W, Wh, D_DIM * C_DIM);
    // 2. x -> xT f16 [B,N,C]
    transpose_convert_x<<<dim3(N_DIM / 32, C_DIM / 32, B_DIM), dim3(32, 8), 0, stream>>>(x, xT);
    // 3. q[b] = W @ x[b]  : NT(A=Wh [D,C], B=xT[b] [N,C]) -> q [D,N]
    gemm_nt<0><<<dim3(D_DIM / 128, N_DIM / 128, B_DIM), dim3(256), 0, stream>>>(
        Wh, 0, xT, (size_t)N_DIM * C_DIM, q, (size_t)D_DIM * N_DIM,
        D_DIM, N_DIM, C_DIM, nullptr, nullptr, 0);
    // 4. BN stats
    bn_stats<<<dim3(D_DIM), dim3(256), 0, stream>>>(q, gamma, bn_beta, stats);
    // 5. h = mish(BN(q)) : h [B,D,N] f16 + hT [B,N,D] f16
    bn_mish<<<dim3(N_DIM / 32, D_DIM / 32, B_DIM), dim3(32, 8), 0, stream>>>(q, stats, h, hT);

    // 6-7. energy + softmax
    if (eb == 16) {
        gemm_nt<0><<<dim3(N_DIM / 128, N_DIM / 128, B_DIM), dim3(256), 0, stream>>>(
            hT, (size_t)N_DIM * D_DIM, hT, (size_t)N_DIM * D_DIM, energy, (size_t)N_DIM * N_DIM,
            N_DIM, N_DIM, D_DIM, nullptr, nullptr, 0);
        softmax_rows<<<dim3(N_DIM, B_DIM), dim3(256), 0, stream>>>(
            energy, (size_t)N_DIM * N_DIM, attn, (size_t)N_DIM * N_DIM);
    } else {
        for (int b = 0; b < B_DIM; ++b) {
            const _Float16* hTb = hT + (size_t)b * N_DIM * D_DIM;
            gemm_nt<0><<<dim3(N_DIM / 128, N_DIM / 128, 1), dim3(256), 0, stream>>>(
                hTb, 0, hTb, 0, energy, 0, N_DIM, N_DIM, D_DIM, nullptr, nullptr, 0);
            _Float16* attnb = attn + (ab == 16 ? (size_t)b * N_DIM * N_DIM : 0);
            softmax_rows<<<dim3(N_DIM, 1), dim3(256), 0, stream>>>(energy, 0, attnb, 0);
            if (ab == 1) {
                // 8 (per-batch fallback): out[b] = beta*(h[b] @ attn^T) + h[b]
                const _Float16* hb = h + (size_t)b * D_DIM * N_DIM;
                gemm_nt<1><<<dim3(D_DIM / 128, N_DIM / 128, 1), dim3(256), 0, stream>>>(
                    hb, 0, attnb, 0, out + (size_t)b * D_DIM * N_DIM, 0,
                    D_DIM, N_DIM, N_DIM, beta, hb, 0);
            }
        }
    }
    // 8. batched: out = beta*(h @ attn^T) + h
    if (ab == 16) {
        gemm_nt<1><<<dim3(D_DIM / 128, N_DIM / 128, B_DIM), dim3(256), 0, stream>>>(
            h, (size_t)D_DIM * N_DIM, attn, (size_t)N_DIM * N_DIM, out, (size_t)D_DIM * N_DIM,
            D_DIM, N_DIM, N_DIM, beta, h, (size_t)D_DIM * N_DIM);
    }
}

// Round 2
// 587.701 us; speedup vs baseline: 1.7465x; 1.7465x over previous
//
#include <hip/hip_runtime.h>
#include <cstdint>
#include <cstddef>

#define B_DIM 16
#define C_DIM 512
#define D_DIM 512
#define N_DIM 2048

typedef _Float16 half8  __attribute__((ext_vector_type(8)));
typedef _Float16 half4v __attribute__((ext_vector_type(4)));
typedef float    floatx4 __attribute__((ext_vector_type(4)));

__device__ __forceinline__ void gload_lds16(const _Float16* g, _Float16* l)
{
    // async global->LDS, 16B per lane. LDS dest is wave-uniform base + lane*16.
    __builtin_amdgcn_global_load_lds((const __attribute__((address_space(1))) void*)g,
                                     (__attribute__((address_space(3))) void*)l,
                                     16, 0, 0);
}

// ---------------------------------------------------------------------------
// NT GEMM: C[M,Ncols] = A[M,K] (f16 rm) * B[Ncols,K]^T (f16 rm)
// 128x128 tile, BK=32, 4 waves (2x2), 4x4 16x16x32 MFMA frags per wave.
// m97 structure: linear LDS [128][32], global_load_lds width-16 staging,
// 2 barriers per K-step.
// EPI==1: C = beta*acc + (float)H   (H laid out like C)
// ---------------------------------------------------------------------------
template<int EPI, typename OutT>
__global__ __launch_bounds__(256, 2)
void gemm_nt(const _Float16* __restrict__ A, size_t strideA,
             const _Float16* __restrict__ Bm, size_t strideB,
             OutT* __restrict__ Cm, size_t strideC,
             int M, int Ncols, int K,
             const float* __restrict__ beta_ptr,
             const _Float16* __restrict__ Hm, size_t strideH)
{
    constexpr int BK = 32;
    __shared__ _Float16 sA[128 * BK];
    __shared__ _Float16 sB[128 * BK];

    const int bz = blockIdx.z;
    const _Float16* Ab = A  + (size_t)bz * strideA;
    const _Float16* Bb = Bm + (size_t)bz * strideB;

    const int m0 = blockIdx.x * 128;
    const int n0 = blockIdx.y * 128;

    const int tid  = threadIdx.x;
    const int lane = tid & 63;
    const int wv   = tid >> 6;              // wave id 0..3
    const int wr   = (tid >> 7) & 1;        // wave row (2x2 waves, 64x64 out each)
    const int wc   = (tid >> 6) & 1;        // wave col

    // staging: each wave covers 16 rows (16 x 64B = 1KB); lane -> row (l>>2), 16B chunk (l&3)
    const int srow = wv * 16 + (lane >> 2);     // 0..63 across the 4 waves
    const int sk   = (lane & 3) * 8;            // half offset within the 32-half row

    const _Float16* gA0 = Ab + (size_t)(m0 + srow)      * K + sk;
    const _Float16* gA1 = Ab + (size_t)(m0 + srow + 64) * K + sk;
    const _Float16* gB0 = Bb + (size_t)(n0 + srow)      * K + sk;
    const _Float16* gB1 = Bb + (size_t)(n0 + srow + 64) * K + sk;

    _Float16* lA0 = &sA[(wv * 16)      * BK];   // wave-uniform LDS bases
    _Float16* lA1 = &sA[(64 + wv * 16) * BK];
    _Float16* lB0 = &sB[(wv * 16)      * BK];
    _Float16* lB1 = &sB[(64 + wv * 16) * BK];

    // fragment read addresses: row = lane&15, k = (lane>>4)*8 (contiguous 8 halfs)
    const int fr = lane & 15;
    const int fk = (lane >> 4) * 8;
    const _Float16* fA = &sA[(wr * 64 + fr) * BK + fk];
    const _Float16* fB = &sB[(wc * 64 + fr) * BK + fk];

    floatx4 acc[4][4] = {};

    for (int k0 = 0; k0 < K; k0 += BK) {
        __syncthreads();                    // previous compute done reading LDS
        gload_lds16(gA0 + k0, lA0);
        gload_lds16(gA1 + k0, lA1);
        gload_lds16(gB0 + k0, lB0);
        gload_lds16(gB1 + k0, lB1);
        __syncthreads();                    // vmcnt(0) drain before barrier -> tile visible
        half8 af[4], bf[4];
        #pragma unroll
        for (int i = 0; i < 4; ++i) af[i] = *(const half8*)(fA + i * 16 * BK);
        #pragma unroll
        for (int j = 0; j < 4; ++j) bf[j] = *(const half8*)(fB + j * 16 * BK);
        #pragma unroll
        for (int i = 0; i < 4; ++i)
            #pragma unroll
            for (int j = 0; j < 4; ++j)
                acc[i][j] = __builtin_amdgcn_mfma_f32_16x16x32_f16(af[i], bf[j], acc[i][j], 0, 0, 0);
    }

    float beta = 0.0f;
    const _Float16* Hb = nullptr;
    if (EPI == 1) { beta = beta_ptr[0]; Hb = Hm + (size_t)bz * strideH; }
    OutT* Cb = Cm + (size_t)bz * strideC;

    // C/D layout (verified): col = lane&15, row = (lane>>4)*4 + r
    #pragma unroll
    for (int i = 0; i < 4; ++i) {
        const int rowb = m0 + wr * 64 + i * 16 + ((lane >> 4) << 2);
        #pragma unroll
        for (int j = 0; j < 4; ++j) {
            const int col = n0 + wc * 64 + j * 16 + (lane & 15);
            #pragma unroll
            for (int r = 0; r < 4; ++r) {
                size_t idx = (size_t)(rowb + r) * Ncols + col;
                float v = acc[i][j][r];
                if (EPI == 1) v = beta * v + (float)Hb[idx];
                Cb[idx] = (OutT)v;
            }
        }
    }
}

// ---------------------------------------------------------------------------
__global__ void convert_w_kernel(const float* __restrict__ W, _Float16* __restrict__ Wh, int n)
{
    int i = blockIdx.x * 256 + threadIdx.x;
    if (i < n) Wh[i] = (_Float16)W[i];
}

// x [B,C,N] f32 -> xT [B,N,C] f16   (32x32 LDS tile transpose)
__global__ void transpose_convert_x(const float* __restrict__ x, _Float16* __restrict__ xT)
{
    __shared__ float tile[32][33];
    const int bz = blockIdx.z;
    const int n0 = blockIdx.x * 32;
    const int c0 = blockIdx.y * 32;
    const int tx = threadIdx.x, ty = threadIdx.y;
    const float* xb = x + (size_t)bz * C_DIM * N_DIM;
    #pragma unroll
    for (int j = 0; j < 4; ++j)
        tile[ty + j * 8][tx] = xb[(size_t)(c0 + ty + j * 8) * N_DIM + n0 + tx];
    __syncthreads();
    _Float16* xtb = xT + (size_t)bz * N_DIM * C_DIM;
    #pragma unroll
    for (int j = 0; j < 4; ++j)
        xtb[(size_t)(n0 + ty + j * 8) * C_DIM + c0 + tx] = (_Float16)tile[tx][ty + j * 8];
}

// per-channel BN stats over (B,N): stats[d] = (scale, bias); q is f16
__global__ __launch_bounds__(256)
void bn_stats(const _Float16* __restrict__ q, const float* __restrict__ gamma,
              const float* __restrict__ bn_beta, float2* __restrict__ stats)
{
    const int d = blockIdx.x;
    const int tid = threadIdx.x;
    float s = 0.f, ss = 0.f;
    for (int b = 0; b < B_DIM; ++b) {
        const _Float16* row = q + ((size_t)b * D_DIM + d) * N_DIM;
        half8 v = *(const half8*)(row + tid * 8);   // 256 threads x 8 halfs = 2048
        #pragma unroll
        for (int j = 0; j < 8; ++j) {
            float f = (float)v[j];
            s += f; ss += f * f;
        }
    }
    #pragma unroll
    for (int off = 32; off; off >>= 1) {
        s  += __shfl_down(s,  off, 64);
        ss += __shfl_down(ss, off, 64);
    }
    __shared__ float red[8];
    const int wv = tid >> 6;
    if ((tid & 63) == 0) { red[wv] = s; red[4 + wv] = ss; }
    __syncthreads();
    if (tid == 0) {
        s  = red[0] + red[1] + red[2] + red[3];
        ss = red[4] + red[5] + red[6] + red[7];
        const float inv = 1.0f / (float)(B_DIM * N_DIM);
        float mean = s * inv;
        float var  = ss * inv - mean * mean;
        float scale = gamma[d] * rsqrtf(var + 1e-5f);
        stats[d] = make_float2(scale, bn_beta[d] - mean * scale);
    }
}

// mish(x) = x * tanh(softplus(x)) == x * ((1+e^x)^2 - 1) / ((1+e^x)^2 + 1)  (exact identity)
__device__ __forceinline__ float mishf(float v)
{
    float t = __expf(fminf(v, 30.0f));       // clamp: (u-1)/(u+1) -> 1 anyway for v>30
    float u = 1.0f + t;
    u *= u;                                  // (1+e^x)^2
    return v * (u - 1.0f) * __builtin_amdgcn_rcpf(u + 1.0f);
}

// q [B,D,N] f16 -> h [B,D,N] f16  and  hT [B,N,D] f16 (BN + mish fused, tiled transpose)
__global__ void bn_mish(const _Float16* __restrict__ q, const float2* __restrict__ stats,
                        _Float16* __restrict__ h, _Float16* __restrict__ hT)
{
    __shared__ float tile[32][33];
    const int bz = blockIdx.z;
    const int n0 = blockIdx.x * 32;
    const int d0 = blockIdx.y * 32;
    const int tx = threadIdx.x, ty = threadIdx.y;
    const _Float16* qb = q + (size_t)bz * D_DIM * N_DIM;
    _Float16* hb = h + (size_t)bz * D_DIM * N_DIM;
    #pragma unroll
    for (int j = 0; j < 4; ++j) {
        int d = d0 + ty + j * 8;
        float2 sc = stats[d];
        float v  = (float)qb[(size_t)d * N_DIM + n0 + tx];
        float hv = mishf(v * sc.x + sc.y);
        tile[ty + j * 8][tx] = hv;
        hb[(size_t)d * N_DIM + n0 + tx] = (_Float16)hv;
    }
    __syncthreads();
    _Float16* htb = hT + (size_t)bz * N_DIM * D_DIM;
    #pragma unroll
    for (int j = 0; j < 4; ++j)
        htb[(size_t)(n0 + ty + j * 8) * D_DIM + d0 + tx] = (_Float16)tile[tx][ty + j * 8];
}

// row softmax: energy [*,N] f32 -> attn [*,N] f16, one block per row
__global__ __launch_bounds__(256)
void softmax_rows(const float* __restrict__ energy, size_t strideE,
                  _Float16* __restrict__ attn, size_t strideAt)
{
    const int n = blockIdx.x;
    const int b = blockIdx.y;
    const float* row = energy + (size_t)b * strideE + (size_t)n * N_DIM;
    _Float16*   orow = attn   + (size_t)b * strideAt + (size_t)n * N_DIM;
    const int tid = threadIdx.x;
    float4 v0 = *(const float4*)(row + tid * 4);
    float4 v1 = *(const float4*)(row + 1024 + tid * 4);
    float mx = fmaxf(fmaxf(fmaxf(v0.x, v0.y), fmaxf(v0.z, v0.w)),
                     fmaxf(fmaxf(v1.x, v1.y), fmaxf(v1.z, v1.w)));
    #pragma unroll
    for (int off = 32; off; off >>= 1) mx = fmaxf(mx, __shfl_down(mx, off, 64));
    __shared__ float redm[4], reds[4];
    const int wv = tid >> 6;
    if ((tid & 63) == 0) redm[wv] = mx;
    __syncthreads();
    mx = fmaxf(fmaxf(redm[0], redm[1]), fmaxf(redm[2], redm[3]));
    float e0 = __expf(v0.x - mx), e1 = __expf(v0.y - mx), e2 = __expf(v0.z - mx), e3 = __expf(v0.w - mx);
    float e4 = __expf(v1.x - mx), e5 = __expf(v1.y - mx), e6 = __expf(v1.z - mx), e7 = __expf(v1.w - mx);
    float s = e0 + e1 + e2 + e3 + e4 + e5 + e6 + e7;
    #pragma unroll
    for (int off = 32; off; off >>= 1) s += __shfl_down(s, off, 64);
    if ((tid & 63) == 0) reds[wv] = s;
    __syncthreads();
    s = reds[0] + reds[1] + reds[2] + reds[3];
    const float inv = 1.0f / s;
    half4v o0 = { (_Float16)(e0 * inv), (_Float16)(e1 * inv), (_Float16)(e2 * inv), (_Float16)(e3 * inv) };
    half4v o1 = { (_Float16)(e4 * inv), (_Float16)(e5 * inv), (_Float16)(e6 * inv), (_Float16)(e7 * inv) };
    *(half4v*)(orow + tid * 4)        = o0;
    *(half4v*)(orow + 1024 + tid * 4) = o1;
}

// ---------------------------------------------------------------------------
extern "C" void kernel_launch(void* const* d_in, const int* in_sizes, int n_in,
                              void* d_out, int out_size, void* d_ws, size_t ws_size,
                              hipStream_t stream)
{
    const float* x       = (const float*)d_in[0];
    const float* W       = (const float*)d_in[1];
    const float* gamma   = (const float*)d_in[2];
    const float* bn_beta = (const float*)d_in[3];
    const float* beta    = (const float*)d_in[4];
    float* out = (float*)d_out;

    char* ws = (char*)d_ws;
    size_t off = 0;
    auto take = [&](size_t bytes) -> char* {
        char* p = ws + off;
        off = (off + bytes + 255) & ~(size_t)255;
        return p;
    };

    _Float16* xT    = (_Float16*)take((size_t)B_DIM * N_DIM * C_DIM * 2);  // later aliased as hT
    _Float16* q     = (_Float16*)take((size_t)B_DIM * D_DIM * N_DIM * 2);  // f16 now
    _Float16* h     = (_Float16*)take((size_t)B_DIM * D_DIM * N_DIM * 2);
    _Float16* Wh    = (_Float16*)take((size_t)D_DIM * C_DIM * 2);
    float2*   stats = (float2*)  take((size_t)D_DIM * sizeof(float2));
    _Float16* hT    = xT;                                                   // xT dead after GEMM1

    const size_t eSz = (size_t)N_DIM * N_DIM * 4;   // fp32 energy per batch
    const size_t aSz = (size_t)N_DIM * N_DIM * 2;   // fp16 attn per batch
    const size_t fixedEnd = off;

    int eb, ab;  // batches materialized for energy / attn
    if      (ws_size >= fixedEnd + 16 * eSz + 16 * aSz + 1024) { eb = 16; ab = 16; }
    else if (ws_size >= fixedEnd +      eSz + 16 * aSz + 1024) { eb = 1;  ab = 16; }
    else                                                        { eb = 1;  ab = 1;  }

    float*    energy = (float*)   take((size_t)eb * eSz);
    _Float16* attn   = (_Float16*)take((size_t)ab * aSz);

    // 1. W -> f16
    convert_w_kernel<<<dim3((D_DIM * C_DIM + 255) / 256), dim3(256), 0, stream>>>(W, Wh, D_DIM * C_DIM);
    // 2. x -> xT f16 [B,N,C]
    transpose_convert_x<<<dim3(N_DIM / 32, C_DIM / 32, B_DIM), dim3(32, 8), 0, stream>>>(x, xT);
    // 3. q[b] = W @ x[b]  : NT(A=Wh [D,C], B=xT[b] [N,C]) -> q [D,N] f16
    gemm_nt<0, _Float16><<<dim3(D_DIM / 128, N_DIM / 128, B_DIM), dim3(256), 0, stream>>>(
        Wh, 0, xT, (size_t)N_DIM * C_DIM, q, (size_t)D_DIM * N_DIM,
        D_DIM, N_DIM, C_DIM, nullptr, nullptr, 0);
    // 4. BN stats
    bn_stats<<<dim3(D_DIM), dim3(256), 0, stream>>>(q, gamma, bn_beta, stats);
    // 5. h = mish(BN(q)) : h [B,D,N] f16 + hT [B,N,D] f16
    bn_mish<<<dim3(N_DIM / 32, D_DIM / 32, B_DIM), dim3(32, 8), 0, stream>>>(q, stats, h, hT);

    // 6-7. energy + softmax
    if (eb == 16) {
        gemm_nt<0, float><<<dim3(N_DIM / 128, N_DIM / 128, B_DIM), dim3(256), 0, stream>>>(
            hT, (size_t)N_DIM * D_DIM, hT, (size_t)N_DIM * D_DIM, energy, (size_t)N_DIM * N_DIM,
            N_DIM, N_DIM, D_DIM, nullptr, nullptr, 0);
        softmax_rows<<<dim3(N_DIM, B_DIM), dim3(256), 0, stream>>>(
            energy, (size_t)N_DIM * N_DIM, attn, (size_t)N_DIM * N_DIM);
    } else {
        for (int b = 0; b < B_DIM; ++b) {
            const _Float16* hTb = hT + (size_t)b * N_DIM * D_DIM;
            gemm_nt<0, float><<<dim3(N_DIM / 128, N_DIM / 128, 1), dim3(256), 0, stream>>>(
                hTb, 0, hTb, 0, energy, 0, N_DIM, N_DIM, D_DIM, nullptr, nullptr, 0);
            _Float16* attnb = attn + (ab == 16 ? (size_t)b * N_DIM * N_DIM : 0);
            softmax_rows<<<dim3(N_DIM, 1), dim3(256), 0, stream>>>(energy, 0, attnb, 0);
            if (ab == 1) {
                // 8 (per-batch fallback): out[b] = beta*(h[b] @ attn^T) + h[b]
                const _Float16* hb = h + (size_t)b * D_DIM * N_DIM;
                gemm_nt<1, float><<<dim3(D_DIM / 128, N_DIM / 128, 1), dim3(256), 0, stream>>>(
                    hb, 0, attnb, 0, out + (size_t)b * D_DIM * N_DIM, 0,
                    D_DIM, N_DIM, N_DIM, beta, hb, 0);
            }
        }
    }
    // 8. batched: out = beta*(h @ attn^T) + h
    if (ab == 16) {
        gemm_nt<1, float><<<dim3(D_DIM / 128, N_DIM / 128, B_DIM), dim3(256), 0, stream>>>(
            h, (size_t)D_DIM * N_DIM, attn, (size_t)N_DIM * N_DIM, out, (size_t)D_DIM * N_DIM,
            D_DIM, N_DIM, N_DIM, beta, h, (size_t)D_DIM * N_DIM);
    }
}

// Round 4
// 471.772 us; speedup vs baseline: 2.1757x; 1.2457x over previous
//
#include <hip/hip_runtime.h>
#include <cstdint>
#include <cstddef>

#define B_DIM 16
#define C_DIM 512
#define D_DIM 512
#define N_DIM 2048

typedef _Float16 half8  __attribute__((ext_vector_type(8)));
typedef float    floatx4 __attribute__((ext_vector_type(4)));

__device__ __forceinline__ void gload_lds16(const _Float16* g, _Float16* l)
{
    // async global->LDS, 16B per lane. LDS dest is wave-uniform base + lane*16 (linear).
    __builtin_amdgcn_global_load_lds((const __attribute__((address_space(1))) void*)g,
                                     (__attribute__((address_space(3))) void*)l,
                                     16, 0, 0);
}

// ---------------------------------------------------------------------------
// NT GEMM: C[M,Ncols] = A[M,K] (f16 rm) * B[Ncols,K]^T (f16 rm)
// 128x128 tile, BK=64 (128B rows = 8 x 16B chunks), 4 waves (2x2),
// 4x4 16x16x32 MFMA frags per wave, 2 k-subs per K-step.
// T2 XOR-swizzle (rule #21, both sides): LDS content at [row][ck] holds
// global chunk ck^(row&7); staging pre-swizzles the GLOBAL source address
// (linear global_load_lds dest), fragment reads XOR the chunk index.
// T1 XCD-chunked block swizzle (bijective; nwg % 8 == 0 for all our grids).
// EPI==1: C = beta*acc + (float)H   (H laid out like C)
// ---------------------------------------------------------------------------
template<int EPI, typename OutT>
__global__ __launch_bounds__(256, 2)
void gemm_nt(const _Float16* __restrict__ A, size_t strideA,
             const _Float16* __restrict__ Bm, size_t strideB,
             OutT* __restrict__ Cm, size_t strideC,
             int M, int Ncols, int K,
             const float* __restrict__ beta_ptr,
             const _Float16* __restrict__ Hm, size_t strideH)
{
    constexpr int BK = 64;                      // halfs per row (128 B)
    __shared__ _Float16 sA[128 * BK];
    __shared__ _Float16 sB[128 * BK];

    // --- XCD-chunked bijective block swizzle (T1) ---
    const int gx = gridDim.x, gy = gridDim.y;
    const int nwg = gx * gy * gridDim.z;
    int flat = blockIdx.x + gx * (blockIdx.y + gy * blockIdx.z);
    const int q8 = nwg >> 3;                    // nwg % 8 == 0 for all our launches
    flat = (flat & 7) * q8 + (flat >> 3);
    const int bx = flat % gx;
    const int by = (flat / gx) % gy;
    const int bz = flat / (gx * gy);

    const _Float16* Ab = A  + (size_t)bz * strideA;
    const _Float16* Bb = Bm + (size_t)bz * strideB;

    const int m0 = bx * 128;
    const int n0 = by * 128;

    const int tid  = threadIdx.x;
    const int lane = tid & 63;
    const int wv   = tid >> 6;
    const int wr   = (tid >> 7) & 1;            // wave row (2x2 waves, 64x64 out each)
    const int wc   = (tid >> 6) & 1;            // wave col
    const int fr   = lane & 15;
    const int hi   = lane >> 4;

    // staging: per pass p (0..3) block covers 32 rows; lane row = p*32 + (tid>>3),
    // chunk = tid&7. Source chunk pre-swizzled: ck_src = (tid&7) ^ (row&7).
    const int srow = tid >> 3;                  // 0..31 (row within pass group)
    const int sk   = ((tid & 7) ^ (srow & 7)) * 8;   // halfs

    const _Float16* gA0 = Ab + (size_t)(m0 + srow) * K + sk;
    const _Float16* gB0 = Bb + (size_t)(n0 + srow) * K + sk;
    _Float16* lA = &sA[(wv * 8) * BK];          // wave-uniform LDS bases (linear dest)
    _Float16* lB = &sB[(wv * 8) * BK];

    // fragment chunk indices (row&7 == fr&7 for all frags): ch[sub] = (sub*4+hi)^(fr&7)
    const int ch0 = ((0 * 4 + hi) ^ (fr & 7)) * 8;  // half offset of chunk
    const int ch1 = ((1 * 4 + hi) ^ (fr & 7)) * 8;
    const _Float16* fA = &sA[(wr * 64 + fr) * BK];
    const _Float16* fB = &sB[(wc * 64 + fr) * BK];

    floatx4 acc[4][4] = {};

    for (int k0 = 0; k0 < K; k0 += BK) {
        __syncthreads();                        // previous compute done reading LDS
        #pragma unroll
        for (int p = 0; p < 4; ++p) {
            gload_lds16(gA0 + (size_t)(p * 32) * K + k0, lA + p * 32 * BK);
            gload_lds16(gB0 + (size_t)(p * 32) * K + k0, lB + p * 32 * BK);
        }
        __syncthreads();                        // vmcnt(0) drain -> tile visible
        #pragma unroll
        for (int sub = 0; sub < 2; ++sub) {
            const int ch = (sub == 0) ? ch0 : ch1;
            half8 af[4], bf[4];
            #pragma unroll
            for (int i = 0; i < 4; ++i) af[i] = *(const half8*)(fA + i * 16 * BK + ch);
            #pragma unroll
            for (int j = 0; j < 4; ++j) bf[j] = *(const half8*)(fB + j * 16 * BK + ch);
            #pragma unroll
            for (int i = 0; i < 4; ++i)
                #pragma unroll
                for (int j = 0; j < 4; ++j)
                    acc[i][j] = __builtin_amdgcn_mfma_f32_16x16x32_f16(af[i], bf[j], acc[i][j], 0, 0, 0);
        }
    }

    float beta = 0.0f;
    const _Float16* Hb = nullptr;
    if (EPI == 1) { beta = beta_ptr[0]; Hb = Hm + (size_t)bz * strideH; }
    OutT* Cb = Cm + (size_t)bz * strideC;

    // C/D layout: col = lane&15, row = (lane>>4)*4 + r
    #pragma unroll
    for (int i = 0; i < 4; ++i) {
        const int rowb = m0 + wr * 64 + i * 16 + (hi << 2);
        #pragma unroll
        for (int j = 0; j < 4; ++j) {
            const int col = n0 + wc * 64 + j * 16 + fr;
            #pragma unroll
            for (int r = 0; r < 4; ++r) {
                size_t idx = (size_t)(rowb + r) * Ncols + col;
                float v = acc[i][j][r];
                if (EPI == 1) v = beta * v + (float)Hb[idx];
                Cb[idx] = (OutT)v;
            }
        }
    }
}

// ---------------------------------------------------------------------------
__global__ void convert_w_kernel(const float* __restrict__ W, _Float16* __restrict__ Wh, int n)
{
    int i = blockIdx.x * 256 + threadIdx.x;
    if (i < n) Wh[i] = (_Float16)W[i];
}

// x [B,C,N] f32 -> xT [B,N,C] f16   (32x32 LDS tile transpose)
__global__ void transpose_convert_x(const float* __restrict__ x, _Float16* __restrict__ xT)
{
    __shared__ float tile[32][33];
    const int bz = blockIdx.z;
    const int n0 = blockIdx.x * 32;
    const int c0 = blockIdx.y * 32;
    const int tx = threadIdx.x, ty = threadIdx.y;
    const float* xb = x + (size_t)bz * C_DIM * N_DIM;
    #pragma unroll
    for (int j = 0; j < 4; ++j)
        tile[ty + j * 8][tx] = xb[(size_t)(c0 + ty + j * 8) * N_DIM + n0 + tx];
    __syncthreads();
    _Float16* xtb = xT + (size_t)bz * N_DIM * C_DIM;
    #pragma unroll
    for (int j = 0; j < 4; ++j)
        xtb[(size_t)(n0 + ty + j * 8) * C_DIM + c0 + tx] = (_Float16)tile[tx][ty + j * 8];
}

// per-channel BN stats over (B,N): stats[d] = (scale, bias); q is f16
__global__ __launch_bounds__(256)
void bn_stats(const _Float16* __restrict__ q, const float* __restrict__ gamma,
              const float* __restrict__ bn_beta, float2* __restrict__ stats)
{
    const int d = blockIdx.x;
    const int tid = threadIdx.x;
    float s = 0.f, ss = 0.f;
    for (int b = 0; b < B_DIM; ++b) {
        const _Float16* row = q + ((size_t)b * D_DIM + d) * N_DIM;
        half8 v = *(const half8*)(row + tid * 8);   // 256 threads x 8 halfs = 2048
        #pragma unroll
        for (int j = 0; j < 8; ++j) {
            float f = (float)v[j];
            s += f; ss += f * f;
        }
    }
    #pragma unroll
    for (int off = 32; off; off >>= 1) {
        s  += __shfl_down(s,  off, 64);
        ss += __shfl_down(ss, off, 64);
    }
    __shared__ float red[8];
    const int wv = tid >> 6;
    if ((tid & 63) == 0) { red[wv] = s; red[4 + wv] = ss; }
    __syncthreads();
    if (tid == 0) {
        s  = red[0] + red[1] + red[2] + red[3];
        ss = red[4] + red[5] + red[6] + red[7];
        const float inv = 1.0f / (float)(B_DIM * N_DIM);
        float mean = s * inv;
        float var  = ss * inv - mean * mean;
        float scale = gamma[d] * rsqrtf(var + 1e-5f);
        stats[d] = make_float2(scale, bn_beta[d] - mean * scale);
    }
}

// mish(x) = x * tanh(softplus(x)) == x * ((1+e^x)^2 - 1) / ((1+e^x)^2 + 1)
__device__ __forceinline__ float mishf(float v)
{
    float t = __expf(fminf(v, 30.0f));
    float u = 1.0f + t;
    u *= u;
    return v * (u - 1.0f) * __builtin_amdgcn_rcpf(u + 1.0f);
}

// q [B,D,N] f16 -> h [B,D,N] f16  and  hT [B,N,D] f16 (BN + mish fused, tiled transpose)
__global__ void bn_mish(const _Float16* __restrict__ q, const float2* __restrict__ stats,
                        _Float16* __restrict__ h, _Float16* __restrict__ hT)
{
    __shared__ float tile[32][33];
    const int bz = blockIdx.z;
    const int n0 = blockIdx.x * 32;
    const int d0 = blockIdx.y * 32;
    const int tx = threadIdx.x, ty = threadIdx.y;
    const _Float16* qb = q + (size_t)bz * D_DIM * N_DIM;
    _Float16* hb = h + (size_t)bz * D_DIM * N_DIM;
    #pragma unroll
    for (int j = 0; j < 4; ++j) {
        int d = d0 + ty + j * 8;
        float2 sc = stats[d];
        float v  = (float)qb[(size_t)d * N_DIM + n0 + tx];
        float hv = mishf(v * sc.x + sc.y);
        tile[ty + j * 8][tx] = hv;
        hb[(size_t)d * N_DIM + n0 + tx] = (_Float16)hv;
    }
    __syncthreads();
    _Float16* htb = hT + (size_t)bz * N_DIM * D_DIM;
    #pragma unroll
    for (int j = 0; j < 4; ++j)
        htb[(size_t)(n0 + ty + j * 8) * D_DIM + d0 + tx] = (_Float16)tile[tx][ty + j * 8];
}

// row softmax: energy [*,N] f16 -> attn [*,N] f16, one block (256 thr) per row
__global__ __launch_bounds__(256)
void softmax_rows(const _Float16* __restrict__ energy, size_t strideE,
                  _Float16* __restrict__ attn, size_t strideAt)
{
    const int n = blockIdx.x;
    const int b = blockIdx.y;
    const _Float16* row = energy + (size_t)b * strideE + (size_t)n * N_DIM;
    _Float16*      orow = attn   + (size_t)b * strideAt + (size_t)n * N_DIM;
    const int tid = threadIdx.x;
    half8 v = *(const half8*)(row + tid * 8);
    float f[8];
    #pragma unroll
    for (int j = 0; j < 8; ++j) f[j] = (float)v[j];
    float mx = f[0];
    #pragma unroll
    for (int j = 1; j < 8; ++j) mx = fmaxf(mx, f[j]);
    #pragma unroll
    for (int off = 32; off; off >>= 1) mx = fmaxf(mx, __shfl_down(mx, off, 64));
    __shared__ float redm[4], reds[4];
    const int wv = tid >> 6;
    if ((tid & 63) == 0) redm[wv] = mx;
    __syncthreads();
    mx = fmaxf(fmaxf(redm[0], redm[1]), fmaxf(redm[2], redm[3]));
    float s = 0.f;
    #pragma unroll
    for (int j = 0; j < 8; ++j) { f[j] = __expf(f[j] - mx); s += f[j]; }
    #pragma unroll
    for (int off = 32; off; off >>= 1) s += __shfl_down(s, off, 64);
    if ((tid & 63) == 0) reds[wv] = s;
    __syncthreads();
    s = reds[0] + reds[1] + reds[2] + reds[3];
    const float inv = 1.0f / s;
    half8 o;
    #pragma unroll
    for (int j = 0; j < 8; ++j) o[j] = (_Float16)(f[j] * inv);
    *(half8*)(orow + tid * 8) = o;
}

// ---------------------------------------------------------------------------
extern "C" void kernel_launch(void* const* d_in, const int* in_sizes, int n_in,
                              void* d_out, int out_size, void* d_ws, size_t ws_size,
                              hipStream_t stream)
{
    const float* x       = (const float*)d_in[0];
    const float* W       = (const float*)d_in[1];
    const float* gamma   = (const float*)d_in[2];
    const float* bn_beta = (const float*)d_in[3];
    const float* beta    = (const float*)d_in[4];
    float* out = (float*)d_out;

    char* ws = (char*)d_ws;
    size_t off = 0;
    auto take = [&](size_t bytes) -> char* {
        char* p = ws + off;
        off = (off + bytes + 255) & ~(size_t)255;
        return p;
    };

    _Float16* xT    = (_Float16*)take((size_t)B_DIM * N_DIM * C_DIM * 2);  // later aliased as hT
    _Float16* q     = (_Float16*)take((size_t)B_DIM * D_DIM * N_DIM * 2);
    _Float16* h     = (_Float16*)take((size_t)B_DIM * D_DIM * N_DIM * 2);
    _Float16* Wh    = (_Float16*)take((size_t)D_DIM * C_DIM * 2);
    float2*   stats = (float2*)  take((size_t)D_DIM * sizeof(float2));
    _Float16* hT    = xT;                                                   // xT dead after GEMM1

    const size_t eSz = (size_t)N_DIM * N_DIM * 2;   // fp16 energy per batch
    const size_t aSz = (size_t)N_DIM * N_DIM * 2;   // fp16 attn per batch
    const size_t fixedEnd = off;

    int eb, ab;  // batches materialized for energy / attn
    if      (ws_size >= fixedEnd + 16 * eSz + 16 * aSz + 1024) { eb = 16; ab = 16; }
    else if (ws_size >= fixedEnd +      eSz + 16 * aSz + 1024) { eb = 1;  ab = 16; }
    else                                                        { eb = 1;  ab = 1;  }

    _Float16* energy = (_Float16*)take((size_t)eb * eSz);
    _Float16* attn   = (_Float16*)take((size_t)ab * aSz);

    // 1. W -> f16
    convert_w_kernel<<<dim3((D_DIM * C_DIM + 255) / 256), dim3(256), 0, stream>>>(W, Wh, D_DIM * C_DIM);
    // 2. x -> xT f16 [B,N,C]
    transpose_convert_x<<<dim3(N_DIM / 32, C_DIM / 32, B_DIM), dim3(32, 8), 0, stream>>>(x, xT);
    // 3. q[b] = W @ x[b]  : NT(A=Wh [D,C], B=xT[b] [N,C]) -> q [D,N] f16
    gemm_nt<0, _Float16><<<dim3(D_DIM / 128, N_DIM / 128, B_DIM), dim3(256), 0, stream>>>(
        Wh, 0, xT, (size_t)N_DIM * C_DIM, q, (size_t)D_DIM * N_DIM,
        D_DIM, N_DIM, C_DIM, nullptr, nullptr, 0);
    // 4. BN stats
    bn_stats<<<dim3(D_DIM), dim3(256), 0, stream>>>(q, gamma, bn_beta, stats);
    // 5. h = mish(BN(q)) : h [B,D,N] f16 + hT [B,N,D] f16
    bn_mish<<<dim3(N_DIM / 32, D_DIM / 32, B_DIM), dim3(32, 8), 0, stream>>>(q, stats, h, hT);

    // 6-7. energy (f16) + softmax
    if (eb == 16) {
        gemm_nt<0, _Float16><<<dim3(N_DIM / 128, N_DIM / 128, B_DIM), dim3(256), 0, stream>>>(
            hT, (size_t)N_DIM * D_DIM, hT, (size_t)N_DIM * D_DIM, energy, (size_t)N_DIM * N_DIM,
            N_DIM, N_DIM, D_DIM, nullptr, nullptr, 0);
        softmax_rows<<<dim3(N_DIM, B_DIM), dim3(256), 0, stream>>>(
            energy, (size_t)N_DIM * N_DIM, attn, (size_t)N_DIM * N_DIM);
    } else {
        for (int b = 0; b < B_DIM; ++b) {
            const _Float16* hTb = hT + (size_t)b * N_DIM * D_DIM;
            gemm_nt<0, _Float16><<<dim3(N_DIM / 128, N_DIM / 128, 1), dim3(256), 0, stream>>>(
                hTb, 0, hTb, 0, energy, 0, N_DIM, N_DIM, D_DIM, nullptr, nullptr, 0);
            _Float16* attnb = attn + (ab == 16 ? (size_t)b * N_DIM * N_DIM : 0);
            softmax_rows<<<dim3(N_DIM, 1), dim3(256), 0, stream>>>(energy, 0, attnb, 0);
            if (ab == 1) {
                const _Float16* hb = h + (size_t)b * D_DIM * N_DIM;
                gemm_nt<1, float><<<dim3(D_DIM / 128, N_DIM / 128, 1), dim3(256), 0, stream>>>(
                    hb, 0, attnb, 0, out + (size_t)b * D_DIM * N_DIM, 0,
                    D_DIM, N_DIM, N_DIM, beta, hb, 0);
            }
        }
    }
    // 8. batched: out = beta*(h @ attn^T) + h
    if (ab == 16) {
        gemm_nt<1, float><<<dim3(D_DIM / 128, N_DIM / 128, B_DIM), dim3(256), 0, stream>>>(
            h, (size_t)D_DIM * N_DIM, attn, (size_t)N_DIM * N_DIM, out, (size_t)D_DIM * N_DIM,
            D_DIM, N_DIM, N_DIM, beta, h, (size_t)D_DIM * N_DIM);
    }
}